// Round 2
// baseline (1279.896 us; speedup 1.0000x reference)
//
#include <hip/hip_runtime.h>
#include <hip/hip_bf16.h>
#include <math.h>

typedef unsigned short u16;
typedef __attribute__((ext_vector_type(8))) short bf16x8;
typedef __attribute__((ext_vector_type(4))) float f32x4;

// B=4, T=2048, D=1024, H=16, DK=64, DV=128, CHUNK=64, N_CHUNKS=32

__device__ __forceinline__ u16 f2bf(float f) {
  union { float f; unsigned u; } a; a.f = f;
  unsigned u = a.u;
  unsigned r = (u + 0x7fffu + ((u >> 16) & 1u)) >> 16;
  return (u16)r;
}
__device__ __forceinline__ float bf2f(u16 s) {
  union { unsigned u; float f; } a; a.u = ((unsigned)s) << 16; return a.f;
}

__global__ void k_sentinel(float* out) {
  if (threadIdx.x == 0 && blockIdx.x == 0) out[0] = 1.0e6f;
}

// ---------- x f32 -> bf16 ----------
__global__ __launch_bounds__(256) void k_cvt_x(const float* __restrict__ src, u16* __restrict__ dst) {
  int i = blockIdx.x * 256 + threadIdx.x;   // over n/4 elements
  float4 v = ((const float4*)src)[i];
  ushort4 o;
  o.x = f2bf(v.x); o.y = f2bf(v.y); o.z = f2bf(v.z); o.w = f2bf(v.w);
  ((ushort4*)dst)[i] = o;
}

// ---------- W [K][N] f32 -> [N][K] bf16 (tiled transpose) ----------
__global__ __launch_bounds__(256) void k_transpose(const float* __restrict__ src, u16* __restrict__ dst,
                                                   int K, int N) {
  __shared__ float tile[32][33];
  int n0 = blockIdx.x * 32, k0 = blockIdx.y * 32;
  int tx = threadIdx.x & 31, ty = threadIdx.x >> 5;   // ty 0..7
  for (int r = 0; r < 32; r += 8)
    tile[ty + r][tx] = src[(size_t)(k0 + ty + r) * N + n0 + tx];
  __syncthreads();
  for (int r = 0; r < 32; r += 8)
    dst[(size_t)(n0 + ty + r) * K + k0 + tx] = f2bf(tile[tx][ty + r]);
}

// ---------- bf16 GEMM: C[M][N] = A[M][K] * Bt[N][K]^T ----------
// tile 128x128, BK=32, 4 waves in 2x2, each wave 64x64 via 4x4 frags of 16x16x32
template <bool BF16OUT>
__global__ __launch_bounds__(256) void k_gemm(const u16* __restrict__ A, const u16* __restrict__ Bt,
                                              void* __restrict__ Cv, int N, int K) {
  __shared__ __attribute__((aligned(16))) u16 As[128 * 40];
  __shared__ __attribute__((aligned(16))) u16 Bs[128 * 40];
  int i0 = blockIdx.y * 128, n0 = blockIdx.x * 128;
  int tid = threadIdx.x;
  int lane = tid & 63, w = tid >> 6;
  int wr = (w >> 1) * 64, wc = (w & 1) * 64;
  f32x4 acc[4][4];
#pragma unroll
  for (int m = 0; m < 4; ++m)
#pragma unroll
    for (int n = 0; n < 4; ++n) acc[m][n] = (f32x4){0.f, 0.f, 0.f, 0.f};
  int fr = lane & 15, kb = (lane >> 4) * 8;
  for (int k0 = 0; k0 < K; k0 += 32) {
    __syncthreads();
#pragma unroll
    for (int c = tid; c < 512; c += 256) {
      int row = c >> 2, kc = (c & 3) * 8;
      *(bf16x8*)&As[row * 40 + kc] = *(const bf16x8*)&A[(size_t)(i0 + row) * K + k0 + kc];
      *(bf16x8*)&Bs[row * 40 + kc] = *(const bf16x8*)&Bt[(size_t)(n0 + row) * K + k0 + kc];
    }
    __syncthreads();
    bf16x8 af[4], bfr[4];
#pragma unroll
    for (int m = 0; m < 4; ++m) af[m] = *(const bf16x8*)&As[(wr + m * 16 + fr) * 40 + kb];
#pragma unroll
    for (int n = 0; n < 4; ++n) bfr[n] = *(const bf16x8*)&Bs[(wc + n * 16 + fr) * 40 + kb];
#pragma unroll
    for (int m = 0; m < 4; ++m)
#pragma unroll
      for (int n = 0; n < 4; ++n)
        acc[m][n] = __builtin_amdgcn_mfma_f32_16x16x32_bf16(af[m], bfr[n], acc[m][n], 0, 0, 0);
  }
  int rb = (lane >> 4) * 4, cb = lane & 15;
#pragma unroll
  for (int m = 0; m < 4; ++m)
#pragma unroll
    for (int n = 0; n < 4; ++n) {
      int gr = i0 + wr + m * 16 + rb;
      int gc = n0 + wc + n * 16 + cb;
#pragma unroll
      for (int r = 0; r < 4; ++r) {
        float v = acc[m][n][r];
        if (BF16OUT) ((u16*)Cv)[(size_t)(gr + r) * N + gc] = f2bf(v);
        else         ((float*)Cv)[(size_t)(gr + r) * N + gc] = v;
      }
    }
}

// ---------- RoPE on q (cols 0..1023, *0.125) and k (cols 1024..2047), in place ----------
__global__ __launch_bounds__(256) void k_rope(float* __restrict__ qk) {
  int idx = blockIdx.x * 256 + threadIdx.x;  // B*T*32
  int i = idx & 31;
  int row = idx >> 5;        // b*T + t
  int t = row & 2047;
  float invf = powf(10000.f, -(float)i * (1.f / 32.f));
  float fr = (float)t * invf;
  float s = sinf(fr), c = cosf(fr);
  float* p = qk + (size_t)row * 2048;
#pragma unroll
  for (int h = 0; h < 16; ++h) {
    int c1 = h * 64 + i, c2 = c1 + 32;
    float q1 = p[c1], q2 = p[c2];
    p[c1] = (q1 * c - q2 * s) * 0.125f;
    p[c2] = (q2 * c + q1 * s) * 0.125f;
    float k1 = p[1024 + c1], k2 = p[1024 + c2];
    p[1024 + c1] = k1 * c - k2 * s;
    p[1024 + c2] = k2 * c + k1 * s;
  }
}

// ---------- Fused retention: per (b,h), scan 32 chunks, S in LDS, fused RMSNorm+gate ----------
// o = (q k^T * Dmask) v + (q*cross) @ S ; S = S*cdec + (k*kdec)^T v ; og = norm(o)*gnw*silu(g)
__global__ __launch_bounds__(512) void k_retention(const float* __restrict__ qk, const u16* __restrict__ vg,
                                                   const float* __restrict__ gnw, u16* __restrict__ og) {
  int bh = blockIdx.x;            // b*16 + h
  int h = bh & 15, b = bh >> 4;
  __shared__ float S[64][132];    // [d][e], rows 16B-aligned
  __shared__ float qs[64][66];
  __shared__ float ks[64][66];
  __shared__ __attribute__((aligned(16))) u16 vs[64][136];
  __shared__ float attn[64][66];
  __shared__ float dpow[66];
  int tid = threadIdx.x;
  float gamma = 1.f - exp2f(-5.f - (float)h);
  if (tid <= 64) dpow[tid] = powf(gamma, (float)tid);
  for (int c = tid; c < 64 * 132; c += 512) ((float*)S)[c] = 0.f;
  __syncthreads();
  float cdec = dpow[64];          // gamma^CHUNK
  int i = tid >> 3, sub = tid & 7, e0 = sub * 16;
  float crossi = dpow[i] * gamma; // gamma^(i+1)
  float kw[2];                    // gnw for my e-range (const across chunks)
  float gnwv[16];
#pragma unroll
  for (int c = 0; c < 16; ++c) gnwv[c] = gnw[e0 + c];
  (void)kw;

  for (int n = 0; n < 32; ++n) {
    int rowbase = b * 2048 + n * 64;
    // ---- stage q,k (f32), v (bf16) ----
    for (int c = tid; c < 4096; c += 512) {
      int r = c >> 6, d = c & 63;
      const float* qr = qk + (size_t)(rowbase + r) * 2048;
      qs[r][d] = qr[h * 64 + d];
      ks[r][d] = qr[1024 + h * 64 + d];
    }
    for (int c = tid; c < 1024; c += 512) {
      int r = c >> 4, e8 = (c & 15) * 8;
      *(bf16x8*)&vs[r][e8] = *(const bf16x8*)&vg[(size_t)(rowbase + r) * 4096 + h * 128 + e8];
    }
    __syncthreads();
    // ---- attn[i][j] = (q_i . k_j) * gamma^(i-j), i>=j ----
    for (int c = tid; c < 4096; c += 512) {
      int ai = c >> 6, aj = c & 63;
      float a = 0.f;
      if (ai >= aj) {
        float s = 0.f;
#pragma unroll
        for (int d = 0; d < 64; ++d) s += qs[ai][d] * ks[aj][d];
        a = s * dpow[ai - aj];
      }
      attn[ai][aj] = a;
    }
    __syncthreads();
    // ---- o row i, cols e0..e0+15 ----
    float o[16];
#pragma unroll
    for (int c = 0; c < 16; ++c) o[c] = 0.f;
    for (int j = 0; j < 64; ++j) {
      float a = attn[i][j];
#pragma unroll
      for (int c = 0; c < 16; ++c) o[c] += a * bf2f(vs[j][e0 + c]);
    }
    for (int d = 0; d < 64; ++d) {
      float qv = qs[i][d] * crossi;
#pragma unroll
      for (int c = 0; c < 16; ++c) o[c] += qv * S[d][e0 + c];
    }
    // ---- RMSNorm over 128 (8 lanes x 16) + gate ----
    float ss = 0.f;
#pragma unroll
    for (int c = 0; c < 16; ++c) ss += o[c] * o[c];
    ss += __shfl_xor(ss, 1, 64);
    ss += __shfl_xor(ss, 2, 64);
    ss += __shfl_xor(ss, 4, 64);
    float rms = rsqrtf(ss * (1.f / 128.f) + 1e-5f);
    int row = rowbase + i;
    const u16* gp = vg + (size_t)row * 4096 + 2048 + h * 128 + e0;
    u16* ogp = og + (size_t)row * 2048 + h * 128 + e0;
#pragma unroll
    for (int c = 0; c < 16; ++c) {
      float g = bf2f(gp[c]);
      float y = o[c] * rms * gnwv[c] * (g / (1.f + expf(-g)));
      ogp[c] = f2bf(y);
    }
    __syncthreads();   // all S reads (cross term) done before update
    // ---- S update: S[d][e] = S*cdec + sum_j kdec_j k[j][d] v[j][e]  (d := i) ----
    float acc[16];
#pragma unroll
    for (int c = 0; c < 16; ++c) acc[c] = 0.f;
    for (int j = 0; j < 64; ++j) {
      float kk = ks[j][i] * dpow[63 - j];
#pragma unroll
      for (int c = 0; c < 16; ++c) acc[c] += kk * bf2f(vs[j][e0 + c]);
    }
#pragma unroll
    for (int c = 0; c < 16; ++c) S[i][e0 + c] = S[i][e0 + c] * cdec + acc[c];
    __syncthreads();   // S updated & ks/vs free before next stage
  }
}

extern "C" void kernel_launch(void* const* d_in, const int* in_sizes, int n_in,
                              void* d_out, int out_size, void* d_ws, size_t ws_size,
                              hipStream_t stream) {
  const float* x   = (const float*)d_in[0];
  const float* Wq  = (const float*)d_in[1];
  const float* Wk  = (const float*)d_in[2];
  const float* Wv  = (const float*)d_in[3];
  const float* Wg  = (const float*)d_in[4];
  const float* Wo  = (const float*)d_in[5];
  const float* gnw = (const float*)d_in[6];
  float* out = (float*)d_out;

  const size_t MB = 1024 * 1024;
  char* ws = (char*)d_ws;
  // Layout (164 MB total):
  //   [0,16)    xb bf16 (dead after projections; og bf16 overlays [0,32) later)
  //   [16,20)   Wqkb, [20,28) Wvgb
  //   [32,96)   qk f32
  //   [96,160)  vg bf16
  //   [160,164) Wob
  u16*  xb   = (u16*)(ws + 0 * MB);
  u16*  Wqkb = (u16*)(ws + 16 * MB);
  u16*  Wvgb = (u16*)(ws + 20 * MB);
  float* qk  = (float*)(ws + 32 * MB);
  u16*  vg   = (u16*)(ws + 96 * MB);
  u16*  Wob  = (u16*)(ws + 160 * MB);
  u16*  og   = (u16*)(ws + 0 * MB);   // overlay, 32 MB
  const size_t NEED = 164 * MB;
  if (ws_size < NEED) {               // diagnostic: absmax ~1e6 => workspace too small
    k_sentinel<<<1, 64, 0, stream>>>(out);
    return;
  }

  k_cvt_x<<<8192, 256, 0, stream>>>(x, xb);
  k_transpose<<<dim3(32, 32), 256, 0, stream>>>(Wq, Wqkb, 1024, 1024);
  k_transpose<<<dim3(32, 32), 256, 0, stream>>>(Wk, Wqkb + (size_t)1024 * 1024, 1024, 1024);
  k_transpose<<<dim3(64, 32), 256, 0, stream>>>(Wv, Wvgb, 1024, 2048);
  k_transpose<<<dim3(64, 32), 256, 0, stream>>>(Wg, Wvgb + (size_t)2048 * 1024, 1024, 2048);
  k_transpose<<<dim3(32, 64), 256, 0, stream>>>(Wo, Wob, 2048, 1024);

  k_gemm<false><<<dim3(16, 64), 256, 0, stream>>>(xb, Wqkb, qk, 2048, 1024);
  k_gemm<true ><<<dim3(32, 64), 256, 0, stream>>>(xb, Wvgb, vg, 4096, 1024);
  k_rope<<<1024, 256, 0, stream>>>(qk);
  k_retention<<<64, 512, 0, stream>>>(qk, vg, gnw, og);
  k_gemm<false><<<dim3(8, 64), 256, 0, stream>>>(og, Wob, out, 1024, 2048);
}

// Round 3
// 655.552 us; speedup vs baseline: 1.9524x; 1.9524x over previous
//
#include <hip/hip_runtime.h>
#include <hip/hip_bf16.h>
#include <math.h>

typedef unsigned short u16;
typedef __attribute__((ext_vector_type(8))) short bf16x8;
typedef __attribute__((ext_vector_type(4))) float f32x4;

// B=4, T=2048, D=1024, H=16, DK=64, DV=128, CHUNK=64, N_CHUNKS=32

__device__ __forceinline__ u16 f2bf(float f) {
  union { float f; unsigned u; } a; a.f = f;
  unsigned u = a.u;
  unsigned r = (u + 0x7fffu + ((u >> 16) & 1u)) >> 16;
  return (u16)r;
}
__device__ __forceinline__ float bf2f(u16 s) {
  union { unsigned u; float f; } a; a.u = ((unsigned)s) << 16; return a.f;
}

__global__ void k_sentinel(float* out) {
  if (threadIdx.x == 0 && blockIdx.x == 0) out[0] = 1.0e6f;
}

// ---------- x f32 -> bf16 ----------
__global__ __launch_bounds__(256) void k_cvt_x(const float* __restrict__ src, u16* __restrict__ dst) {
  int i = blockIdx.x * 256 + threadIdx.x;
  float4 v = ((const float4*)src)[i];
  ushort4 o;
  o.x = f2bf(v.x); o.y = f2bf(v.y); o.z = f2bf(v.z); o.w = f2bf(v.w);
  ((ushort4*)dst)[i] = o;
}

// ---------- W [K][N] f32 -> [N][K] bf16 (tiled transpose) ----------
__global__ __launch_bounds__(256) void k_transpose(const float* __restrict__ src, u16* __restrict__ dst,
                                                   int K, int N) {
  __shared__ float tile[32][33];
  int n0 = blockIdx.x * 32, k0 = blockIdx.y * 32;
  int tx = threadIdx.x & 31, ty = threadIdx.x >> 5;
  for (int r = 0; r < 32; r += 8)
    tile[ty + r][tx] = src[(size_t)(k0 + ty + r) * N + n0 + tx];
  __syncthreads();
  for (int r = 0; r < 32; r += 8)
    dst[(size_t)(n0 + ty + r) * K + k0 + tx] = f2bf(tile[tx][ty + r]);
}

// ---------- bf16 GEMM: C[M][N] = A[M][K] * Bt[N][K]^T ----------
template <bool BF16OUT>
__global__ __launch_bounds__(256) void k_gemm(const u16* __restrict__ A, const u16* __restrict__ Bt,
                                              void* __restrict__ Cv, int N, int K) {
  __shared__ __attribute__((aligned(16))) u16 As[128 * 40];
  __shared__ __attribute__((aligned(16))) u16 Bs[128 * 40];
  int i0 = blockIdx.y * 128, n0 = blockIdx.x * 128;
  int tid = threadIdx.x;
  int lane = tid & 63, w = tid >> 6;
  int wr = (w >> 1) * 64, wc = (w & 1) * 64;
  f32x4 acc[4][4];
#pragma unroll
  for (int m = 0; m < 4; ++m)
#pragma unroll
    for (int n = 0; n < 4; ++n) acc[m][n] = (f32x4){0.f, 0.f, 0.f, 0.f};
  int fr = lane & 15, kb = (lane >> 4) * 8;
  for (int k0 = 0; k0 < K; k0 += 32) {
    __syncthreads();
#pragma unroll
    for (int c = tid; c < 512; c += 256) {
      int row = c >> 2, kc = (c & 3) * 8;
      *(bf16x8*)&As[row * 40 + kc] = *(const bf16x8*)&A[(size_t)(i0 + row) * K + k0 + kc];
      *(bf16x8*)&Bs[row * 40 + kc] = *(const bf16x8*)&Bt[(size_t)(n0 + row) * K + k0 + kc];
    }
    __syncthreads();
    bf16x8 af[4], bfr[4];
#pragma unroll
    for (int m = 0; m < 4; ++m) af[m] = *(const bf16x8*)&As[(wr + m * 16 + fr) * 40 + kb];
#pragma unroll
    for (int n = 0; n < 4; ++n) bfr[n] = *(const bf16x8*)&Bs[(wc + n * 16 + fr) * 40 + kb];
#pragma unroll
    for (int m = 0; m < 4; ++m)
#pragma unroll
      for (int n = 0; n < 4; ++n)
        acc[m][n] = __builtin_amdgcn_mfma_f32_16x16x32_bf16(af[m], bfr[n], acc[m][n], 0, 0, 0);
  }
  int rb = (lane >> 4) * 4, cb = lane & 15;
#pragma unroll
  for (int m = 0; m < 4; ++m)
#pragma unroll
    for (int n = 0; n < 4; ++n) {
      int gr = i0 + wr + m * 16 + rb;
      int gc = n0 + wc + n * 16 + cb;
#pragma unroll
      for (int r = 0; r < 4; ++r) {
        float v = acc[m][n][r];
        if (BF16OUT) ((u16*)Cv)[(size_t)(gr + r) * N + gc] = f2bf(v);
        else         ((float*)Cv)[(size_t)(gr + r) * N + gc] = v;
      }
    }
}

// ---------- RoPE in place ----------
__global__ __launch_bounds__(256) void k_rope(float* __restrict__ qk) {
  int idx = blockIdx.x * 256 + threadIdx.x;
  int i = idx & 31;
  int row = idx >> 5;
  int t = row & 2047;
  float invf = powf(10000.f, -(float)i * (1.f / 32.f));
  float fr = (float)t * invf;
  float s = sinf(fr), c = cosf(fr);
  float* p = qk + (size_t)row * 2048;
#pragma unroll
  for (int h = 0; h < 16; ++h) {
    int c1 = h * 64 + i, c2 = c1 + 32;
    float q1 = p[c1], q2 = p[c2];
    p[c1] = (q1 * c - q2 * s) * 0.125f;
    p[c2] = (q2 * c + q1 * s) * 0.125f;
    float k1 = p[1024 + c1], k2 = p[1024 + c2];
    p[1024 + c1] = k1 * c - k2 * s;
    p[1024 + c2] = k2 * c + k1 * s;
  }
}

// ---------- Fused retention v2: 256 blocks = (rq 4) x (bh 64), row-quarter split ----------
// Block (bh, rq): rows gi = rq*16 + [0,16) of every chunk, all 128 e-cols.
// S-update replicated across the 4 rq-blocks (keeps RMSNorm row-local, no HBM buffer).
__global__ __launch_bounds__(512) void k_retention(const float* __restrict__ qk, const u16* __restrict__ vg,
                                                   const float* __restrict__ gnw, u16* __restrict__ og) {
  // blocks sharing bh are 64 apart -> same XCD (round-robin %8) for k/v L2 reuse
  int bh = blockIdx.x & 63, rq = blockIdx.x >> 6;
  int h = bh & 15, b = bh >> 4;
  __shared__ __attribute__((aligned(16))) float S[64][132];    // state [d][e]
  __shared__ __attribute__((aligned(16))) float vsf[64][132];  // v f32 [j][e]
  __shared__ float kst[64][68];    // k transposed [d][j]
  __shared__ float kstd[64][68];   // k*kdec transposed [d][j]
  __shared__ float qs[16][68];     // q rows of this quarter [i][d]
  __shared__ float attn[16][68];   // masked, decayed scores [i][j]
  __shared__ float dpow[80];
  int tid = threadIdx.x;
  float gamma = 1.f - exp2f(-5.f - (float)h);
  if (tid <= 64) dpow[tid] = powf(gamma, (float)tid);
  for (int c = tid; c < 64 * 132; c += 512) ((float*)S)[c] = 0.f;
  __syncthreads();
  float cdec = dpow[64];

  // fixed per-thread roles
  int i = tid >> 5;                 // 0..15 (attn + o/cross row)
  int gi = rq * 16 + i;
  int c4 = (tid & 31) * 4;          // o/cross col group (4 consecutive)
  int j2 = (tid & 31) * 2;          // attn col pair
  int d8 = tid >> 3;                // 0..63 (S-update row)
  int cg = (tid & 7) * 4;           // S-update col base (4 cols x 4 groups of 32)
  float crossi = dpow[gi] * gamma;  // gamma^(gi+1)
  float4 gnw4 = *(const float4*)&gnw[c4];
  int jmax = rq * 16 + 16;

  for (int n = 0; n < 32; ++n) {
    int rowbase = b * 2048 + n * 64;
    // ---- stage ----
    for (int c = tid; c < 1024; c += 512) {           // q: 16 rows x 64
      int r = c >> 6, d = c & 63;
      qs[r][d] = qk[(size_t)(rowbase + rq * 16 + r) * 2048 + h * 64 + d];
    }
    for (int c = tid; c < 4096; c += 512) {           // k: 64 rows x 64, transposed
      int r = c >> 6, d = c & 63;
      float v = qk[(size_t)(rowbase + r) * 2048 + 1024 + h * 64 + d];
      kst[d][r] = v;
      kstd[d][r] = v * dpow[63 - r];
    }
    for (int c = tid; c < 1024; c += 512) {           // v: 64 rows x 128 bf16 -> f32
      int r = c >> 4, e8 = (c & 15) * 8;
      bf16x8 vv = *(const bf16x8*)&vg[(size_t)(rowbase + r) * 4096 + h * 128 + e8];
      f32x4 a, bq;
      a[0] = bf2f((u16)vv[0]); a[1] = bf2f((u16)vv[1]); a[2] = bf2f((u16)vv[2]); a[3] = bf2f((u16)vv[3]);
      bq[0] = bf2f((u16)vv[4]); bq[1] = bf2f((u16)vv[5]); bq[2] = bf2f((u16)vv[6]); bq[3] = bf2f((u16)vv[7]);
      *(f32x4*)&vsf[r][e8] = a;
      *(f32x4*)&vsf[r][e8 + 4] = bq;
    }
    __syncthreads();
    // ---- attn[i][j] = (q_i . k_j) * gamma^(i-j), causal ----
    {
      float s0 = 0.f, s1 = 0.f;
      for (int d = 0; d < 64; ++d) {
        float qv = qs[i][d];
        s0 += qv * kst[d][j2];
        s1 += qv * kst[d][j2 + 1];
      }
      attn[i][j2]     = (gi >= j2)     ? s0 * dpow[gi - j2]     : 0.f;
      attn[i][j2 + 1] = (gi >= j2 + 1) ? s1 * dpow[gi - j2 - 1] : 0.f;
    }
    __syncthreads();
    // ---- S-update accumulate (replicated) ----
    float acc[16];
#pragma unroll
    for (int q = 0; q < 16; ++q) acc[q] = 0.f;
    if (n < 31) {
      for (int j = 0; j < 64; ++j) {
        float kk = kstd[d8][j];
#pragma unroll
        for (int m = 0; m < 4; ++m) {
          f32x4 vv = *(const f32x4*)&vsf[j][cg + 32 * m];
          acc[m * 4 + 0] += kk * vv[0];
          acc[m * 4 + 1] += kk * vv[1];
          acc[m * 4 + 2] += kk * vv[2];
          acc[m * 4 + 3] += kk * vv[3];
        }
      }
    }
    // ---- o = attn@v + crossi * (q @ S) for (row gi, cols c4..c4+3) ----
    float o0 = 0.f, o1 = 0.f, o2 = 0.f, o3 = 0.f;
    for (int j = 0; j < jmax; ++j) {
      float a = attn[i][j];
      f32x4 vv = *(const f32x4*)&vsf[j][c4];
      o0 += a * vv[0]; o1 += a * vv[1]; o2 += a * vv[2]; o3 += a * vv[3];
    }
    float x0 = 0.f, x1 = 0.f, x2 = 0.f, x3 = 0.f;
    for (int d = 0; d < 64; ++d) {
      float qv = qs[i][d];
      f32x4 sv = *(const f32x4*)&S[d][c4];
      x0 += qv * sv[0]; x1 += qv * sv[1]; x2 += qv * sv[2]; x3 += qv * sv[3];
    }
    o0 += crossi * x0; o1 += crossi * x1; o2 += crossi * x2; o3 += crossi * x3;
    // ---- RMSNorm over 128 (32 lanes x 4) + gate, write og bf16 ----
    float ss = o0 * o0 + o1 * o1 + o2 * o2 + o3 * o3;
    ss += __shfl_xor(ss, 1, 64);
    ss += __shfl_xor(ss, 2, 64);
    ss += __shfl_xor(ss, 4, 64);
    ss += __shfl_xor(ss, 8, 64);
    ss += __shfl_xor(ss, 16, 64);
    float rms = rsqrtf(ss * (1.f / 128.f) + 1e-5f);
    {
      int row = rowbase + gi;
      ushort4 gv = *(const ushort4*)&vg[(size_t)row * 4096 + 2048 + h * 128 + c4];
      float g0 = bf2f(gv.x), g1 = bf2f(gv.y), g2 = bf2f(gv.z), g3 = bf2f(gv.w);
      ushort4 st;
      st.x = f2bf(o0 * rms * gnw4.x * (g0 / (1.f + expf(-g0))));
      st.y = f2bf(o1 * rms * gnw4.y * (g1 / (1.f + expf(-g1))));
      st.z = f2bf(o2 * rms * gnw4.z * (g2 / (1.f + expf(-g2))));
      st.w = f2bf(o3 * rms * gnw4.w * (g3 / (1.f + expf(-g3))));
      *(ushort4*)&og[(size_t)row * 2048 + h * 128 + c4] = st;
    }
    __syncthreads();   // all S reads done, acc ready
    // ---- S = S*cdec + acc ----
    if (n < 31) {
#pragma unroll
      for (int m = 0; m < 4; ++m) {
        f32x4 sv = *(const f32x4*)&S[d8][cg + 32 * m];
        sv[0] = sv[0] * cdec + acc[m * 4 + 0];
        sv[1] = sv[1] * cdec + acc[m * 4 + 1];
        sv[2] = sv[2] * cdec + acc[m * 4 + 2];
        sv[3] = sv[3] * cdec + acc[m * 4 + 3];
        *(f32x4*)&S[d8][cg + 32 * m] = sv;
      }
    }
    __syncthreads();   // S visible; kst/kstd/vsf free for next stage
  }
}

extern "C" void kernel_launch(void* const* d_in, const int* in_sizes, int n_in,
                              void* d_out, int out_size, void* d_ws, size_t ws_size,
                              hipStream_t stream) {
  const float* x   = (const float*)d_in[0];
  const float* Wq  = (const float*)d_in[1];
  const float* Wk  = (const float*)d_in[2];
  const float* Wv  = (const float*)d_in[3];
  const float* Wg  = (const float*)d_in[4];
  const float* Wo  = (const float*)d_in[5];
  const float* gnw = (const float*)d_in[6];
  float* out = (float*)d_out;

  const size_t MB = 1024 * 1024;
  char* ws = (char*)d_ws;
  u16*  xb   = (u16*)(ws + 0 * MB);
  u16*  Wqkb = (u16*)(ws + 16 * MB);
  u16*  Wvgb = (u16*)(ws + 20 * MB);
  float* qk  = (float*)(ws + 32 * MB);
  u16*  vg   = (u16*)(ws + 96 * MB);
  u16*  Wob  = (u16*)(ws + 160 * MB);
  u16*  og   = (u16*)(ws + 0 * MB);   // overlay (xb/Wqkb/Wvgb dead by then)
  const size_t NEED = 164 * MB;
  if (ws_size < NEED) {
    k_sentinel<<<1, 64, 0, stream>>>(out);
    return;
  }

  k_cvt_x<<<8192, 256, 0, stream>>>(x, xb);
  k_transpose<<<dim3(32, 32), 256, 0, stream>>>(Wq, Wqkb, 1024, 1024);
  k_transpose<<<dim3(32, 32), 256, 0, stream>>>(Wk, Wqkb + (size_t)1024 * 1024, 1024, 1024);
  k_transpose<<<dim3(64, 32), 256, 0, stream>>>(Wv, Wvgb, 1024, 2048);
  k_transpose<<<dim3(64, 32), 256, 0, stream>>>(Wg, Wvgb + (size_t)2048 * 1024, 1024, 2048);
  k_transpose<<<dim3(32, 64), 256, 0, stream>>>(Wo, Wob, 2048, 1024);

  k_gemm<false><<<dim3(16, 64), 256, 0, stream>>>(xb, Wqkb, qk, 2048, 1024);
  k_gemm<true ><<<dim3(32, 64), 256, 0, stream>>>(xb, Wvgb, vg, 4096, 1024);
  k_rope<<<1024, 256, 0, stream>>>(qk);
  k_retention<<<256, 512, 0, stream>>>(qk, vg, gnw, og);
  k_gemm<false><<<dim3(8, 64), 256, 0, stream>>>(og, Wob, out, 1024, 2048);
}

// Round 4
// 400.827 us; speedup vs baseline: 3.1931x; 1.6355x over previous
//
#include <hip/hip_runtime.h>
#include <hip/hip_bf16.h>
#include <math.h>

typedef unsigned short u16;
typedef unsigned int u32;
typedef __attribute__((ext_vector_type(8))) short bf16x8;
typedef __attribute__((ext_vector_type(4))) float f32x4;

// B=4, T=2048, D=1024, H=16, DK=64, DV=128, CHUNK=64, N_CHUNKS=32

__device__ __forceinline__ u16 f2bf(float f) {
  union { float f; unsigned u; } a; a.f = f;
  unsigned u = a.u;
  unsigned r = (u + 0x7fffu + ((u >> 16) & 1u)) >> 16;
  return (u16)r;
}
__device__ __forceinline__ float bf2f(u16 s) {
  union { unsigned u; float f; } a; a.u = ((unsigned)s) << 16; return a.f;
}

__global__ void k_sentinel(float* out) {
  if (threadIdx.x == 0 && blockIdx.x == 0) out[0] = 1.0e6f;
}

// exact split: f32 -> bf16 hi + bf16 lo (truncation; hi+lo == f to ~2^-16 rel)
__device__ __forceinline__ void split8(const float* __restrict__ p, bf16x8& hi, bf16x8& lo) {
  f32x4 a = *(const f32x4*)p;
  f32x4 b = *(const f32x4*)(p + 4);
  float t[8];
  t[0]=a[0]; t[1]=a[1]; t[2]=a[2]; t[3]=a[3]; t[4]=b[0]; t[5]=b[1]; t[6]=b[2]; t[7]=b[3];
#pragma unroll
  for (int m = 0; m < 8; ++m) {
    union { float f; u32 u; } c; c.f = t[m];
    u16 hb = (u16)(c.u >> 16);
    union { u32 u; float f; } hf; hf.u = c.u & 0xffff0000u;
    union { float f; u32 u; } lw; lw.f = t[m] - hf.f;
    hi[m] = (short)hb;
    lo[m] = (short)(u16)(lw.u >> 16);
  }
}
__device__ __forceinline__ void split8r(const float* t, bf16x8& hi, bf16x8& lo) {
#pragma unroll
  for (int m = 0; m < 8; ++m) {
    union { float f; u32 u; } c; c.f = t[m];
    u16 hb = (u16)(c.u >> 16);
    union { u32 u; float f; } hf; hf.u = c.u & 0xffff0000u;
    union { float f; u32 u; } lw; lw.f = t[m] - hf.f;
    hi[m] = (short)hb;
    lo[m] = (short)(u16)(lw.u >> 16);
  }
}

// ---------- x f32 -> bf16 ----------
__global__ __launch_bounds__(256) void k_cvt_x(const float* __restrict__ src, u16* __restrict__ dst) {
  int i = blockIdx.x * 256 + threadIdx.x;
  float4 v = ((const float4*)src)[i];
  ushort4 o;
  o.x = f2bf(v.x); o.y = f2bf(v.y); o.z = f2bf(v.z); o.w = f2bf(v.w);
  ((ushort4*)dst)[i] = o;
}

// ---------- W [K][N] f32 -> [N][K] bf16 (tiled transpose) ----------
__global__ __launch_bounds__(256) void k_transpose(const float* __restrict__ src, u16* __restrict__ dst,
                                                   int K, int N) {
  __shared__ float tile[32][33];
  int n0 = blockIdx.x * 32, k0 = blockIdx.y * 32;
  int tx = threadIdx.x & 31, ty = threadIdx.x >> 5;
  for (int r = 0; r < 32; r += 8)
    tile[ty + r][tx] = src[(size_t)(k0 + ty + r) * N + n0 + tx];
  __syncthreads();
  for (int r = 0; r < 32; r += 8)
    dst[(size_t)(n0 + ty + r) * K + k0 + tx] = f2bf(tile[tx][ty + r]);
}

// ---------- bf16 GEMM: C[M][N] = A[M][K] * Bt[N][K]^T ----------
template <bool BF16OUT>
__global__ __launch_bounds__(256) void k_gemm(const u16* __restrict__ A, const u16* __restrict__ Bt,
                                              void* __restrict__ Cv, int N, int K) {
  __shared__ __attribute__((aligned(16))) u16 As[128 * 40];
  __shared__ __attribute__((aligned(16))) u16 Bs[128 * 40];
  int i0 = blockIdx.y * 128, n0 = blockIdx.x * 128;
  int tid = threadIdx.x;
  int lane = tid & 63, w = tid >> 6;
  int wr = (w >> 1) * 64, wc = (w & 1) * 64;
  f32x4 acc[4][4];
#pragma unroll
  for (int m = 0; m < 4; ++m)
#pragma unroll
    for (int n = 0; n < 4; ++n) acc[m][n] = (f32x4){0.f, 0.f, 0.f, 0.f};
  int fr = lane & 15, kb = (lane >> 4) * 8;
  for (int k0 = 0; k0 < K; k0 += 32) {
    __syncthreads();
#pragma unroll
    for (int c = tid; c < 512; c += 256) {
      int row = c >> 2, kc = (c & 3) * 8;
      *(bf16x8*)&As[row * 40 + kc] = *(const bf16x8*)&A[(size_t)(i0 + row) * K + k0 + kc];
      *(bf16x8*)&Bs[row * 40 + kc] = *(const bf16x8*)&Bt[(size_t)(n0 + row) * K + k0 + kc];
    }
    __syncthreads();
    bf16x8 af[4], bfr[4];
#pragma unroll
    for (int m = 0; m < 4; ++m) af[m] = *(const bf16x8*)&As[(wr + m * 16 + fr) * 40 + kb];
#pragma unroll
    for (int n = 0; n < 4; ++n) bfr[n] = *(const bf16x8*)&Bs[(wc + n * 16 + fr) * 40 + kb];
#pragma unroll
    for (int m = 0; m < 4; ++m)
#pragma unroll
      for (int n = 0; n < 4; ++n)
        acc[m][n] = __builtin_amdgcn_mfma_f32_16x16x32_bf16(af[m], bfr[n], acc[m][n], 0, 0, 0);
  }
  int rb = (lane >> 4) * 4, cb = lane & 15;
#pragma unroll
  for (int m = 0; m < 4; ++m)
#pragma unroll
    for (int n = 0; n < 4; ++n) {
      int gr = i0 + wr + m * 16 + rb;
      int gc = n0 + wc + n * 16 + cb;
#pragma unroll
      for (int r = 0; r < 4; ++r) {
        float v = acc[m][n][r];
        if (BF16OUT) ((u16*)Cv)[(size_t)(gr + r) * N + gc] = f2bf(v);
        else         ((float*)Cv)[(size_t)(gr + r) * N + gc] = v;
      }
    }
}

// ---------- RoPE in place ----------
__global__ __launch_bounds__(256) void k_rope(float* __restrict__ qk) {
  int idx = blockIdx.x * 256 + threadIdx.x;
  int i = idx & 31;
  int row = idx >> 5;
  int t = row & 2047;
  float invf = powf(10000.f, -(float)i * (1.f / 32.f));
  float fr = (float)t * invf;
  float s = sinf(fr), c = cosf(fr);
  float* p = qk + (size_t)row * 2048;
#pragma unroll
  for (int h = 0; h < 16; ++h) {
    int c1 = h * 64 + i, c2 = c1 + 32;
    float q1 = p[c1], q2 = p[c2];
    p[c1] = (q1 * c - q2 * s) * 0.125f;
    p[c2] = (q2 * c + q1 * s) * 0.125f;
    float k1 = p[1024 + c1], k2 = p[1024 + c2];
    p[1024 + c1] = k1 * c - k2 * s;
    p[1024 + c2] = k2 * c + k1 * s;
  }
}

// ---------- Fused retention v3: MFMA with exact hi/lo splits (no numerics change) ----------
// 256 blocks = (rq 4) x (bh 64). Block owns rows gi = rq*16+[0,16) of each chunk, all 128 e.
// S (64x128 f32) lives in per-wave accumulators (wave w: d-strip [16w,16w+16)); replicated per rq.
// bf16 hi/lo copy of S^T in LDS feeds the cross-term B-fragments (exact split).
__global__ __launch_bounds__(256) void k_retention(const float* __restrict__ qk, const u16* __restrict__ vg,
                                                   const float* __restrict__ gnw, u16* __restrict__ og) {
  int bh = blockIdx.x & 63, rq = blockIdx.x >> 6;
  int h = bh & 15, b = bh >> 4;
  int gi0 = rq * 16;

  __shared__ __attribute__((aligned(16))) float qs[16][68];     // q rows [i][d]
  __shared__ __attribute__((aligned(16))) float ks[64][68];     // k row-major [j][d]
  __shared__ __attribute__((aligned(16))) float kst[64][68];    // k transposed [d][j]
  __shared__ __attribute__((aligned(16))) float attnf[16][68];  // masked attn f32 [i][j]
  __shared__ __attribute__((aligned(16))) u16 vst[128][88];     // v^T bf16 [e][j]
  __shared__ __attribute__((aligned(16))) u16 sst_hi[128][88];  // S^T hi [e][d]
  __shared__ __attribute__((aligned(16))) u16 sst_lo[128][88];  // S^T lo [e][d]
  __shared__ float dpow[72];
  __shared__ float ssred[4][16];

  int tid = threadIdx.x;
  int w = tid >> 6, l = tid & 63;
  int fr = l & 15, fq = l >> 4;           // frag row/col, k-subblock
  float gamma = 1.f - exp2f(-5.f - (float)h);
  if (tid <= 64) dpow[tid] = powf(gamma, (float)tid);
  for (int c = tid; c < 128 * 88 / 2; c += 256) { ((u32*)sst_hi)[c] = 0; ((u32*)sst_lo)[c] = 0; }
  __syncthreads();
  float cdec = dpow[64];

  // static per-lane: kdec for S-update A-frag j positions
  float kdec[2][8];
#pragma unroll
  for (int kh = 0; kh < 2; ++kh)
#pragma unroll
    for (int m = 0; m < 8; ++m) kdec[kh][m] = dpow[63 - (kh * 32 + fq * 8 + m)];
  float gw[2] = { gnw[w * 32 + fr], gnw[w * 32 + 16 + fr] };
  int khmax = (gi0 + 15 < 32) ? 1 : 2;   // attn cols >= 32 are all-masked for rq 0,1

  f32x4 Sacc[8];
#pragma unroll
  for (int te = 0; te < 8; ++te) Sacc[te] = (f32x4){0.f, 0.f, 0.f, 0.f};

  for (int n = 0; n < 32; ++n) {
    int rowbase = b * 2048 + n * 64;
    // ---- A: stage q, k (row + transposed), v^T ----
    {
      int i = tid >> 4, d4 = (tid & 15) * 4;
      *(f32x4*)&qs[i][d4] = *(const f32x4*)&qk[(size_t)(rowbase + gi0 + i) * 2048 + h * 64 + d4];
      int j = tid >> 2;
#pragma unroll
      for (int mq = 0; mq < 4; ++mq) {
        int d4k = (tid & 3) * 4 + mq * 16;
        f32x4 kv = *(const f32x4*)&qk[(size_t)(rowbase + j) * 2048 + 1024 + h * 64 + d4k];
        *(f32x4*)&ks[j][d4k] = kv;
        kst[d4k + 0][j] = kv[0]; kst[d4k + 1][j] = kv[1];
        kst[d4k + 2][j] = kv[2]; kst[d4k + 3][j] = kv[3];
      }
#pragma unroll
      for (int mq = 0; mq < 4; ++mq) {
        int e8 = (tid & 3) * 8 + mq * 32;
        bf16x8 vv = *(const bf16x8*)&vg[(size_t)(rowbase + j) * 4096 + h * 128 + e8];
#pragma unroll
        for (int m = 0; m < 8; ++m) vst[e8 + m][j] = (u16)vv[m];
      }
    }
    __syncthreads();
    // ---- B: attn tile (cols j0 = w*16), exact-split MFMA ----
    bf16x8 qh[2], ql[2];
    split8(&qs[fr][fq * 8], qh[0], ql[0]);
    split8(&qs[fr][32 + fq * 8], qh[1], ql[1]);
    {
      f32x4 at = (f32x4){0.f, 0.f, 0.f, 0.f};
#pragma unroll
      for (int kh = 0; kh < 2; ++kh) {
        bf16x8 kbh, kbl;
        split8(&ks[w * 16 + fr][kh * 32 + fq * 8], kbh, kbl);
        at = __builtin_amdgcn_mfma_f32_16x16x32_bf16(qh[kh], kbh, at, 0, 0, 0);
        at = __builtin_amdgcn_mfma_f32_16x16x32_bf16(qh[kh], kbl, at, 0, 0, 0);
        at = __builtin_amdgcn_mfma_f32_16x16x32_bf16(ql[kh], kbh, at, 0, 0, 0);
      }
#pragma unroll
      for (int r = 0; r < 4; ++r) {
        int i16 = fq * 4 + r;
        int gi = gi0 + i16, j = w * 16 + fr;
        float dec = 0.f;
        int s = gi - j;
        if (s >= 0) dec = dpow[s];
        attnf[i16][j] = at[r] * dec;
      }
    }
    __syncthreads();
    // ---- C: o1 = attn@v, o2 = q@S (exact splits), wave e-strip w*32 ----
    f32x4 o1[2] = { (f32x4){0,0,0,0}, (f32x4){0,0,0,0} };
    f32x4 o2[2] = { (f32x4){0,0,0,0}, (f32x4){0,0,0,0} };
    bf16x8 ath[2], atl[2];
    split8(&attnf[fr][fq * 8], ath[0], atl[0]);
    split8(&attnf[fr][32 + fq * 8], ath[1], atl[1]);
#pragma unroll
    for (int tt = 0; tt < 2; ++tt) {
      int e0 = w * 32 + tt * 16;
#pragma unroll
      for (int kh = 0; kh < 2; ++kh) {
        bf16x8 sh = *(const bf16x8*)&sst_hi[e0 + fr][kh * 32 + fq * 8];
        bf16x8 sl = *(const bf16x8*)&sst_lo[e0 + fr][kh * 32 + fq * 8];
        o2[tt] = __builtin_amdgcn_mfma_f32_16x16x32_bf16(qh[kh], sh, o2[tt], 0, 0, 0);
        o2[tt] = __builtin_amdgcn_mfma_f32_16x16x32_bf16(qh[kh], sl, o2[tt], 0, 0, 0);
        o2[tt] = __builtin_amdgcn_mfma_f32_16x16x32_bf16(ql[kh], sh, o2[tt], 0, 0, 0);
        if (kh < khmax) {
          bf16x8 bv = *(const bf16x8*)&vst[e0 + fr][kh * 32 + fq * 8];
          o1[tt] = __builtin_amdgcn_mfma_f32_16x16x32_bf16(ath[kh], bv, o1[tt], 0, 0, 0);
          o1[tt] = __builtin_amdgcn_mfma_f32_16x16x32_bf16(atl[kh], bv, o1[tt], 0, 0, 0);
        }
      }
    }
    // combine + per-row sumsq partial (this wave's 32 cols)
    float ofin[2][4];
    float ssp[4];
#pragma unroll
    for (int r = 0; r < 4; ++r) {
      int gi = gi0 + fq * 4 + r;
      float cri = dpow[gi + 1];
      float v0 = o1[0][r] + cri * o2[0][r];
      float v1 = o1[1][r] + cri * o2[1][r];
      ofin[0][r] = v0; ofin[1][r] = v1;
      ssp[r] = v0 * v0 + v1 * v1;
    }
#pragma unroll
    for (int r = 0; r < 4; ++r) {
      ssp[r] += __shfl_xor(ssp[r], 1, 64);
      ssp[r] += __shfl_xor(ssp[r], 2, 64);
      ssp[r] += __shfl_xor(ssp[r], 4, 64);
      ssp[r] += __shfl_xor(ssp[r], 8, 64);
    }
    if (fr == 0) {
#pragma unroll
      for (int r = 0; r < 4; ++r) ssred[w][fq * 4 + r] = ssp[r];
    }
    __syncthreads();
    // ---- D: rms + gate + store ----
#pragma unroll
    for (int r = 0; r < 4; ++r) {
      int i16 = fq * 4 + r;
      float tot = ssred[0][i16] + ssred[1][i16] + ssred[2][i16] + ssred[3][i16];
      float rms = rsqrtf(tot * (1.f / 128.f) + 1e-5f);
      int grow = rowbase + gi0 + i16;
#pragma unroll
      for (int tt = 0; tt < 2; ++tt) {
        int col = w * 32 + tt * 16 + fr;
        float g = bf2f(vg[(size_t)grow * 4096 + 2048 + h * 128 + col]);
        float y = ofin[tt][r] * rms * gw[tt] * (g / (1.f + expf(-g)));
        og[(size_t)grow * 2048 + h * 128 + col] = f2bf(y);
      }
    }
    // ---- E: S = cdec*S + (kdec*k)^T @ v  (f32 accumulators; exact-split A) ----
#pragma unroll
    for (int te = 0; te < 8; ++te) {
#pragma unroll
      for (int r = 0; r < 4; ++r) Sacc[te][r] *= cdec;
    }
#pragma unroll
    for (int kh = 0; kh < 2; ++kh) {
      float tmp[8];
      f32x4 ka = *(const f32x4*)&kst[w * 16 + fr][kh * 32 + fq * 8];
      f32x4 kb2 = *(const f32x4*)&kst[w * 16 + fr][kh * 32 + fq * 8 + 4];
#pragma unroll
      for (int m = 0; m < 4; ++m) { tmp[m] = ka[m] * kdec[kh][m]; tmp[m + 4] = kb2[m] * kdec[kh][m + 4]; }
      bf16x8 akh, akl;
      split8r(tmp, akh, akl);
#pragma unroll
      for (int te = 0; te < 8; ++te) {
        bf16x8 bv = *(const bf16x8*)&vst[te * 16 + fr][kh * 32 + fq * 8];
        Sacc[te] = __builtin_amdgcn_mfma_f32_16x16x32_bf16(akh, bv, Sacc[te], 0, 0, 0);
        Sacc[te] = __builtin_amdgcn_mfma_f32_16x16x32_bf16(akl, bv, Sacc[te], 0, 0, 0);
      }
    }
    // write S^T hi/lo for next chunk's cross term (exact split of f32 S)
#pragma unroll
    for (int te = 0; te < 8; ++te) {
#pragma unroll
      for (int r = 0; r < 4; ++r) {
        int d = w * 16 + fq * 4 + r;
        int e = te * 16 + fr;
        union { float f; u32 u; } c; c.f = Sacc[te][r];
        union { u32 u; float f; } hf; hf.u = c.u & 0xffff0000u;
        union { float f; u32 u; } lw; lw.f = Sacc[te][r] - hf.f;
        sst_hi[e][d] = (u16)(c.u >> 16);
        sst_lo[e][d] = (u16)(lw.u >> 16);
      }
    }
    __syncthreads();
  }
}

extern "C" void kernel_launch(void* const* d_in, const int* in_sizes, int n_in,
                              void* d_out, int out_size, void* d_ws, size_t ws_size,
                              hipStream_t stream) {
  const float* x   = (const float*)d_in[0];
  const float* Wq  = (const float*)d_in[1];
  const float* Wk  = (const float*)d_in[2];
  const float* Wv  = (const float*)d_in[3];
  const float* Wg  = (const float*)d_in[4];
  const float* Wo  = (const float*)d_in[5];
  const float* gnw = (const float*)d_in[6];
  float* out = (float*)d_out;

  const size_t MB = 1024 * 1024;
  char* ws = (char*)d_ws;
  u16*  xb   = (u16*)(ws + 0 * MB);
  u16*  Wqkb = (u16*)(ws + 16 * MB);
  u16*  Wvgb = (u16*)(ws + 20 * MB);
  float* qk  = (float*)(ws + 32 * MB);
  u16*  vg   = (u16*)(ws + 96 * MB);
  u16*  Wob  = (u16*)(ws + 160 * MB);
  u16*  og   = (u16*)(ws + 0 * MB);   // overlay (xb/Wqkb/Wvgb dead by then)
  const size_t NEED = 164 * MB;
  if (ws_size < NEED) {
    k_sentinel<<<1, 64, 0, stream>>>(out);
    return;
  }

  k_cvt_x<<<8192, 256, 0, stream>>>(x, xb);
  k_transpose<<<dim3(32, 32), 256, 0, stream>>>(Wq, Wqkb, 1024, 1024);
  k_transpose<<<dim3(32, 32), 256, 0, stream>>>(Wk, Wqkb + (size_t)1024 * 1024, 1024, 1024);
  k_transpose<<<dim3(64, 32), 256, 0, stream>>>(Wv, Wvgb, 1024, 2048);
  k_transpose<<<dim3(64, 32), 256, 0, stream>>>(Wg, Wvgb + (size_t)2048 * 1024, 1024, 2048);
  k_transpose<<<dim3(32, 64), 256, 0, stream>>>(Wo, Wob, 2048, 1024);

  k_gemm<false><<<dim3(16, 64), 256, 0, stream>>>(xb, Wqkb, qk, 2048, 1024);
  k_gemm<true ><<<dim3(32, 64), 256, 0, stream>>>(xb, Wvgb, vg, 4096, 1024);
  k_rope<<<1024, 256, 0, stream>>>(qk);
  k_retention<<<256, 256, 0, stream>>>(qk, vg, gnw, og);
  k_gemm<false><<<dim3(8, 64), 256, 0, stream>>>(og, Wob, out, 1024, 2048);
}